// Round 7
// baseline (275.612 us; speedup 1.0000x reference)
//
#include <hip/hip_runtime.h>
#include <hip/hip_bf16.h>

#define B_  2
#define S_  2048
#define D_  1024
#define H_  16
#define DH_ 64

typedef __attribute__((ext_vector_type(8)))  short  short8;
typedef __attribute__((ext_vector_type(4)))  short  short4b;
typedef __attribute__((ext_vector_type(16))) float  f32x16;

#define MFMA32(A,B,C) __builtin_amdgcn_mfma_f32_32x32x16_bf16(A,B,C,0,0,0)

static __device__ __forceinline__ short bf16b(float x) {
    __hip_bfloat16 h = __float2bfloat16(x);
    return *(short*)&h;
}
static __device__ __forceinline__ float bf16tof(short s) {
    union { unsigned u; float f; } cv;
    cv.u = ((unsigned)(unsigned short)s) << 16;
    return cv.f;
}
static __device__ __forceinline__ void gl2lds(const short* g, short* l) {
    __builtin_amdgcn_global_load_lds(
        (const __attribute__((address_space(1))) unsigned int*)g,
        (__attribute__((address_space(3))) unsigned int*)l, 16, 0, 0);
}
static __device__ __forceinline__ unsigned cvtpk(float a, float b) {
    unsigned r;
    asm("v_cvt_pk_bf16_f32 %0, %1, %2" : "=v"(r) : "v"(a), "v"(b));
    return r;   // low16 = bf16(a), high16 = bf16(b)
}
static __device__ __forceinline__ void pl32swap(unsigned &a, unsigned &b) {
    // a[32:63] <-> b[0:31]
    asm volatile("v_permlane32_swap_b32 %0, %1" : "+v"(a), "+v"(b));
}

// ---------------------------------------------------------------------------
// Merged conversion kernel.
//  bid < 12288 : x [4096x1024] fp32 -> hi/lo bf16 (3 z-slices of 4096 blocks)
//  bid >= 12288: w [k][n] fp32 -> wT hi/lo bf16 [n][k] (LDS-transposed tiles)
// ---------------------------------------------------------------------------
__global__ __launch_bounds__(256)
void conv_all(const float* __restrict__ q, const float* __restrict__ k,
              const float* __restrict__ v,
              const float* __restrict__ wq, const float* __restrict__ wk,
              const float* __restrict__ wv, char* __restrict__ ws) {
    __shared__ short HiT[64][80];
    __shared__ short LoT[64][80];
    const int bid = blockIdx.x;
    const int t   = threadIdx.x;
    if (bid < 12288) {
        const int z   = bid >> 12;           // 4096 blocks per z
        const int xb  = bid & 4095;
        const float* src = z == 0 ? q : z == 1 ? k : v;
        short* hi = (short*)(ws + (size_t)z * 16777216);
        short* lo = hi + 4194304;
        const int i = (xb * 256 + t) * 4;
        float4 xv = *(const float4*)&src[i];
        const float* xf = (const float*)&xv;
        short4b h4, l4;
#pragma unroll
        for (int e = 0; e < 4; ++e) {
            short hb = bf16b(xf[e]);
            h4[e] = hb;
            l4[e] = bf16b(xf[e] - bf16tof(hb));
        }
        *(short4b*)&hi[i] = h4;
        *(short4b*)&lo[i] = l4;
        return;
    }
    const int wid = bid - 12288;             // 768 blocks: 3 z x 256
    const int z   = wid >> 8;
    const int rem = wid & 255;
    const int k0  = (rem & 15) << 6, n0 = (rem >> 4) << 6;
    const float* w = z == 0 ? wq : z == 1 ? wk : wv;
    short* oh = (short*)(ws + 50331648 + (size_t)z * 4194304);  // 48MB + z*4MB
    short* ol = oh + 1048576;

    const int kr = t >> 2, c4 = (t & 3) * 16;
    const float* srow = w + (size_t)(k0 + kr) * 1024 + n0 + c4;
#pragma unroll
    for (int u = 0; u < 16; u += 4) {
        float4 f = *(const float4*)&srow[u];
        const float* ff = (const float*)&f;
#pragma unroll
        for (int e = 0; e < 4; ++e) {
            int nl = c4 + u + e;
            short hb = bf16b(ff[e]);
            HiT[nl][kr] = hb;
            LoT[nl][kr] = bf16b(ff[e] - bf16tof(hb));
        }
    }
    __syncthreads();
    const int nl = t >> 2, kc = (t & 3) * 16;
    size_t off = (size_t)(n0 + nl) * 1024 + k0 + kc;
    *(short8*)&oh[off]     = *(const short8*)&HiT[nl][kc];
    *(short8*)&oh[off + 8] = *(const short8*)&HiT[nl][kc + 8];
    *(short8*)&ol[off]     = *(const short8*)&LoT[nl][kc];
    *(short8*)&ol[off + 8] = *(const short8*)&LoT[nl][kc + 8];
}

// ---------------------------------------------------------------------------
// MFMA hi/lo projection GEMM. Tile 128x128, BK=32, 4 waves (64x64 each).
// Round-7: LDS 64KB -> 48KB so 3 blocks/CU fit (768 blocks = 3x256, tail-free
// packing; was 2/CU = 512+256 two-round = 75%). A stays gl2lds double-buffered
// (32KB); B is single-buffered (16KB) reg-staged: issue 4 global_load_dwordx4
// at tile head -> compute -> barrier -> vmcnt(0) -> swizzled ds_write_b128.
// Compute-phase reads and MFMA order unchanged -> bit-identical output.
// ---------------------------------------------------------------------------
#define AHI_ 0
#define ALO_ 4096
#define BHI_ 16384
#define BLO_ 20480

__global__ __launch_bounds__(256, 3)
void proj_mfma(const short* __restrict__ xh0, const short* __restrict__ xl0,
               const short* __restrict__ xh1, const short* __restrict__ xl1,
               const short* __restrict__ xh2, const short* __restrict__ xl2,
               const short* __restrict__ wh0, const short* __restrict__ wl0,
               const short* __restrict__ wh1, const short* __restrict__ wl1,
               const short* __restrict__ wh2, const short* __restrict__ wl2,
               short* __restrict__ qh, short* __restrict__ ql,
               short* __restrict__ kh, short* __restrict__ kl,
               short* __restrict__ vt) {
    // 48 KB: A dbuf (2 x (Ahi 8K + Alo 8K) = 32K) + B single (Bhi 8K + Blo 8K)
    __shared__ __align__(16) short lds[24576];
    const int z  = blockIdx.z;
    const int m0 = blockIdx.y * 128;
    const int n0 = blockIdx.x * 128;
    const int t = threadIdx.x, lane = t & 63, w = t >> 6;
    const int l31 = lane & 31, hh = lane >> 5;

    const short* xh = z == 0 ? xh0 : z == 1 ? xh1 : xh2;
    const short* xl = z == 0 ? xl0 : z == 1 ? xl1 : xl2;
    const short* wh = z == 0 ? wh0 : z == 1 ? wh1 : wh2;
    const short* wl = z == 0 ? wl0 : z == 1 ? wl1 : wl2;

    // A staging (gl2lds): 4 insts/thread, 1024 16B-chunks per kstep
    const short* gsrcA[4];
    short*       ldstA[4];
#pragma unroll
    for (int j = 0; j < 4; ++j) {
        int sub = w + ((j & 1) << 2);         // 0..7
        int cc  = (sub << 6) | lane;          // 0..511
        int row = cc >> 2, p = cc & 3;
        int kc  = p ^ ((row & 3) ^ ((row >> 2) & 3));
        const short* base = (j < 2) ? xh : xl;
        gsrcA[j] = base + (size_t)(m0 + row) * 1024 + kc * 8;
        ldstA[j] = &lds[((j < 2) ? AHI_ : ALO_) + sub * 512];   // wave-uniform
    }
    // B staging (reg->LDS, swizzled write): 4 chunks/thread
    const short* gsrcB[4];
    int ldsoB[4];
#pragma unroll
    for (int m = 0; m < 4; ++m) {
        int cc  = t + ((m & 1) << 8);         // 0..511
        int row = cc >> 2, p = cc & 3;
        int sw  = (row & 3) ^ ((row >> 2) & 3);
        const short* base = (m < 2) ? wh : wl;
        gsrcB[m] = base + (size_t)(n0 + row) * 1024 + p * 8;
        ldsoB[m] = ((m < 2) ? BHI_ : BLO_) + row * 32 + (p ^ sw) * 8;
    }

    const int rm0 = ((w & 1) << 6) + l31, rm1 = rm0 + 32;
    const int rn0 = ((w >> 1) << 6) + l31, rn1 = rn0 + 32;
    const int swm = (rm0 & 3) ^ ((rm0 >> 2) & 3);   // same for rm1
    const int swn = (rn0 & 3) ^ ((rn0 >> 2) & 3);

    f32x16 accs[2][2] = {};
    short8 breg[4];

    // prologue: A(0) -> buf0, B(0) -> regs -> LDS
#pragma unroll
    for (int j = 0; j < 4; ++j)
        gl2lds(gsrcA[j], ldstA[j]);
#pragma unroll
    for (int m = 0; m < 4; ++m)
        breg[m] = *(const short8*)(gsrcB[m]);
    asm volatile("s_waitcnt vmcnt(0)" ::: "memory");
#pragma unroll
    for (int m = 0; m < 4; ++m)
        *(short8*)&lds[ldsoB[m]] = breg[m];

    for (int kt = 0; kt < 32; ++kt) {
        const int cb = (kt & 1) << 13;        // current A buffer (shorts)
        asm volatile("s_waitcnt lgkmcnt(0)" ::: "memory");   // my B writes done
        __builtin_amdgcn_s_barrier();                        // all B/A published
        __builtin_amdgcn_sched_barrier(0);
        if (kt < 31) {
            const int ab = ((kt + 1) & 1) << 13;             // next A buffer
#pragma unroll
            for (int j = 0; j < 4; ++j)
                gl2lds(gsrcA[j] + (kt + 1) * 32, ldstA[j] + ab);
#pragma unroll
            for (int m = 0; m < 4; ++m)
                breg[m] = *(const short8*)(gsrcB[m] + (kt + 1) * 32);
        }
        __builtin_amdgcn_sched_barrier(0);    // loads issued before compute
        __builtin_amdgcn_s_setprio(1);
#pragma unroll
        for (int ks = 0; ks < 2; ++ks) {
            const int kc = (ks << 1) | hh;
            const int om = ((kc ^ swm) << 3) + cb;
            const int on = (kc ^ swn) << 3;
            short8 ah0 = *(const short8*)&lds[AHI_ + rm0 * 32 + om];
            short8 ah1 = *(const short8*)&lds[AHI_ + rm1 * 32 + om];
            short8 al0 = *(const short8*)&lds[ALO_ + rm0 * 32 + om];
            short8 al1 = *(const short8*)&lds[ALO_ + rm1 * 32 + om];
            short8 bh0 = *(const short8*)&lds[BHI_ + rn0 * 32 + on];
            short8 bh1 = *(const short8*)&lds[BHI_ + rn1 * 32 + on];
            short8 bl0 = *(const short8*)&lds[BLO_ + rn0 * 32 + on];
            short8 bl1 = *(const short8*)&lds[BLO_ + rn1 * 32 + on];
            accs[0][0] = MFMA32(ah0, bh0, accs[0][0]);
            accs[0][1] = MFMA32(ah0, bh1, accs[0][1]);
            accs[1][0] = MFMA32(ah1, bh0, accs[1][0]);
            accs[1][1] = MFMA32(ah1, bh1, accs[1][1]);
            accs[0][0] = MFMA32(ah0, bl0, accs[0][0]);
            accs[0][1] = MFMA32(ah0, bl1, accs[0][1]);
            accs[1][0] = MFMA32(ah1, bl0, accs[1][0]);
            accs[1][1] = MFMA32(ah1, bl1, accs[1][1]);
            accs[0][0] = MFMA32(al0, bh0, accs[0][0]);
            accs[0][1] = MFMA32(al0, bh1, accs[0][1]);
            accs[1][0] = MFMA32(al1, bh0, accs[1][0]);
            accs[1][1] = MFMA32(al1, bh1, accs[1][1]);
        }
        __builtin_amdgcn_s_setprio(0);
        __builtin_amdgcn_sched_barrier(0);
        __builtin_amdgcn_s_barrier();         // compute done -> LDS-B writable
        if (kt < 31) {
            // A(kt+1) gl2lds + B(kt+1) global loads complete; write B to LDS
            asm volatile("s_waitcnt vmcnt(0)" ::: "memory");
#pragma unroll
            for (int m = 0; m < 4; ++m)
                *(short8*)&lds[ldsoB[m]] = breg[m];
        }
    }

    const int qm = w & 1, qn = w >> 1;
    const int bb = m0 >> 11;
    const int sbase = (m0 & 2047) + qm * 64;
    if (z < 2) {
        short* oh = z == 0 ? qh : kh;
        short* ol = z == 0 ? ql : kl;
        const float qs = (z == 0) ? 0.125f : 1.0f;   // fold attn scale into Q
#pragma unroll
        for (int mt = 0; mt < 2; ++mt)
#pragma unroll
        for (int nt = 0; nt < 2; ++nt) {
            int n_g = n0 + qn * 64 + nt * 32 + l31;
            int h = n_g >> 6, d = n_g & 63;
#pragma unroll
            for (int r = 0; r < 16; ++r) {
                int s = sbase + mt * 32 + (r & 3) + 8 * (r >> 2) + 4 * hh;
                size_t off = (((size_t)(bb * 16 + h) * 2048 + s) << 6) + d;
                float a = accs[mt][nt][r] * qs;
                short hb = bf16b(a);
                oh[off] = hb;
                ol[off] = bf16b(a - bf16tof(hb));
            }
        }
    } else {
#pragma unroll
        for (int mt = 0; mt < 2; ++mt)
#pragma unroll
        for (int nt = 0; nt < 2; ++nt) {
            int n_g = n0 + qn * 64 + nt * 32 + l31;
            int h = n_g >> 6, d = n_g & 63;
            size_t vbase = ((size_t)(bb * 16 + h) * 64 + d) * 2048;
#pragma unroll
            for (int r2 = 0; r2 < 4; ++r2) {
                int s0 = sbase + mt * 32 + 8 * r2 + 4 * hh;
                short4b pk;
#pragma unroll
                for (int a2 = 0; a2 < 4; ++a2)
                    pk[a2] = bf16b(accs[mt][nt][r2 * 4 + a2]);
                *(short4b*)&vt[vbase + s0] = pk;
            }
        }
    }
}

// ---------------------------------------------------------------------------
// MFMA flash attention (unchanged from round 6).
// ---------------------------------------------------------------------------
__global__ __launch_bounds__(256, 2)
void attn_mfma(const short* __restrict__ Qhi, const short* __restrict__ Qlo,
               const short* __restrict__ Khi, const short* __restrict__ Klo,
               const short* __restrict__ Vt,  float* __restrict__ out) {
    __shared__ __align__(16) short SBUF[24576];   // 48KB: Khi|Klo|Vt (dbuf each)
    __shared__ float svp[4][64];
    __shared__ float svs[64];
#define KhiS (SBUF)
#define KloS (SBUF + 8192)
#define VtS  (SBUF + 16384)

    const int t     = threadIdx.x;
    const int lane  = t & 63;
    const int w     = t >> 6;
    const int l31   = lane & 31;
    const int hh    = lane >> 5;
    const int bh    = blockIdx.x;
    const int yy    = blockIdx.y;
    const int qt    = (yy < 8) ? yy : 23 - yy;
    const int q0    = qt * 128;
    const int myq   = q0 + w * 32 + l31;
    const int myq_min = q0 + w * 32;
    const int ktend = 2 * qt + 2;

    const size_t basebh = (size_t)bh * S_ * DH_;

    // ---- in-block V suffix sum over the all-masked tail ----
    {
        const int s_begin = ktend * 64;
        float part = 0.f;
        const short* vrow = Vt + basebh + (size_t)lane * S_;
        for (int s = s_begin + w * 8; s < S_; s += 32) {
            short8 vv = *(const short8*)&vrow[s];
#pragma unroll
            for (int e = 0; e < 8; ++e) part += bf16tof(vv[e]);
        }
        svp[w][lane] = part;
    }
    __syncthreads();
    if (t < 64)
        svs[t] = svp[0][t] + svp[1][t] + svp[2][t] + svp[3][t];
    // (consumed only in the epilogue; the loop's per-tile barriers order it)

    short8 qh[4], ql[4];
    {
        const short* qr = Qhi + basebh + (size_t)myq * DH_;
        const short* lr = Qlo + basebh + (size_t)myq * DH_;
#pragma unroll
        for (int kf = 0; kf < 4; ++kf) {
            int dofs = kf * 16 + hh * 8;
            qh[kf] = *(const short8*)(qr + dofs);
            ql[kf] = *(const short8*)(lr + dofs);
        }
    }

    // staging descriptors: 512 16B-chunks per 64x64 tile, 2 per thread.
    // chunk i -> lds row r=i>>3, chunk c=i&7; content = global chunk c^(r&7).
    const int i1 = (w << 6) | lane;       // 0..255
    const int i2 = 256 + i1;              // 256..511
    const int r1 = i1 >> 3, c1 = (i1 & 7) ^ (r1 & 7);
    const int r2 = i2 >> 3, c2 = (i2 & 7) ^ (r2 & 7);
    const short* gKh1 = Khi + basebh + (size_t)r1 * 64 + c1 * 8;
    const short* gKh2 = Khi + basebh + (size_t)r2 * 64 + c2 * 8;
    const short* gKl1 = Klo + basebh + (size_t)r1 * 64 + c1 * 8;
    const short* gKl2 = Klo + basebh + (size_t)r2 * 64 + c2 * 8;
    const short* gV1  = Vt  + basebh + (size_t)r1 * S_ + c1 * 8;
    const short* gV2  = Vt  + basebh + (size_t)r2 * S_ + c2 * 8;
    const int wub = w << 9;               // wave-uniform lds base (shorts)

#define ASTAGE(KT, BUF) do {                                                  \
        const int ka_ = (KT) * 4096, va_ = (KT) * 64, bo_ = (BUF) * 4096;     \
        gl2lds(gKh1 + ka_, &KhiS[bo_ + wub]);                                 \
        gl2lds(gKh2 + ka_, &KhiS[bo_ + 2048 + wub]);                          \
        gl2lds(gKl1 + ka_, &KloS[bo_ + wub]);                                 \
        gl2lds(gKl2 + ka_, &KloS[bo_ + 2048 + wub]);                          \
        gl2lds(gV1  + va_, &VtS [bo_ + wub]);                                 \
        gl2lds(gV2  + va_, &VtS [bo_ + 2048 + wub]);                          \
    } while (0)

    float m_run = -INFINITY, l_run = 0.f;
    f32x16 oT0 = {}, oT1 = {};

    const int sw0 = l31 & 7;              // read-swizzle ((l31+32)&7 == l31&7)

    ASTAGE(0, 0);

    for (int kt = 0; kt < ktend; ++kt) {
        const int bo = (kt & 1) << 12;
        // own tile-kt loads (issued last iter / prologue) must be complete
        // before the barrier; barrier then publishes all waves' staging.
        asm volatile("s_waitcnt vmcnt(0)" ::: "memory");
        __builtin_amdgcn_s_barrier();
        __builtin_amdgcn_sched_barrier(0);   // no hoisting above the barrier
        if (kt + 1 < ktend)
            ASTAGE(kt + 1, (kt & 1) ^ 1);
        __builtin_amdgcn_sched_barrier(0);   // keep stage issue before compute

        f32x16 acc0 = {}, acc1 = {};
        __builtin_amdgcn_s_setprio(1);
#pragma unroll
        for (int kf = 0; kf < 4; ++kf) {
            const int cs = ((2 * kf + hh) ^ sw0) << 3;
            short8 k0h = *(const short8*)&KhiS[bo + l31 * 64 + cs];
            short8 k0l = *(const short8*)&KloS[bo + l31 * 64 + cs];
            short8 k1h = *(const short8*)&KhiS[bo + (l31 + 32) * 64 + cs];
            short8 k1l = *(const short8*)&KloS[bo + (l31 + 32) * 64 + cs];
            acc0 = MFMA32(k0h, qh[kf], acc0);
            acc0 = MFMA32(k0h, ql[kf], acc0);
            acc0 = MFMA32(k0l, qh[kf], acc0);
            acc1 = MFMA32(k1h, qh[kf], acc1);
            acc1 = MFMA32(k1h, ql[kf], acc1);
            acc1 = MFMA32(k1l, qh[kf], acc1);
        }
        __builtin_amdgcn_s_setprio(0);

        float vals[32];
        float tmax;
        if (kt * 64 + 63 <= myq_min) {
            // fully-unmasked tile (wave-uniform): vals = acc directly
            float t0 = -INFINITY, t1 = -INFINITY;
#pragma unroll
            for (int r = 0; r < 16; ++r) {
                vals[r]      = acc0[r];
                vals[16 + r] = acc1[r];
                t0 = fmaxf(t0, acc0[r]);
                t1 = fmaxf(t1, acc1[r]);
            }
            tmax = fmaxf(t0, t1);
        } else {
            tmax = -INFINITY;
#pragma unroll
            for (int r = 0; r < 16; ++r) {
                int key0 = kt * 64 + ((r & 3) + 8 * (r >> 2) + 4 * hh);
                float v0 = (key0 <= myq)      ? acc0[r] : -8.0f;
                float v1 = (key0 + 32 <= myq) ? acc1[r] : -8.0f;
                vals[r] = v0;
                vals[16 + r] = v1;
                tmax = fmaxf(tmax, fmaxf(v0, v1));
            }
        }
        tmax = fmaxf(tmax, __shfl_xor(tmax, 32, 64));
        // defer-max (T13): keep m_run when the whole wave's tile-max is
        // within +8 of it; P is then bounded by e^8 (bf16-safe).
        const bool defer = __all(tmax <= m_run + 8.0f);
        if (!defer) {
            float mnew  = fmaxf(m_run, tmax);
            float alpha = __expf(m_run - mnew);
            l_run *= alpha;
#pragma unroll
            for (int r = 0; r < 16; ++r) { oT0[r] *= alpha; oT1[r] *= alpha; }
            m_run = mnew;
        }
        // T12: exp + pack in-register; psum on unrounded values.
        float psum = 0.f;
        unsigned cw[16];
#pragma unroll
        for (int tt = 0; tt < 16; ++tt) {
            float p0 = __expf(vals[2 * tt]     - m_run);
            float p1 = __expf(vals[2 * tt + 1] - m_run);
            psum += p0 + p1;
            cw[tt] = cvtpk(p0, p1);
        }
        psum += __shfl_xor(psum, 32, 64);
        l_run += psum;

        __builtin_amdgcn_s_setprio(1);
#pragma unroll
        for (int kf = 0; kf < 4; ++kf) {
            unsigned w0 = cw[4 * kf],     w1 = cw[4 * kf + 1];
            unsigned w2 = cw[4 * kf + 2], w3 = cw[4 * kf + 3];
            pl32swap(w0, w2);   // w0 = pf word q0, w2 = word q2
            pl32swap(w1, w3);   // w1 = word q1,    w3 = word q3
            union { unsigned u[4]; short8 s8; } pu;
            pu.u[0] = w0; pu.u[1] = w1; pu.u[2] = w2; pu.u[3] = w3;
            const int cs = ((2 * kf + hh) ^ sw0) << 3;
            short8 v0 = *(const short8*)&VtS[bo + l31 * 64 + cs];
            short8 v1 = *(const short8*)&VtS[bo + (l31 + 32) * 64 + cs];
            oT0 = MFMA32(v0, pu.s8, oT0);
            oT1 = MFMA32(v1, pu.s8, oT1);
        }
        __builtin_amdgcn_s_setprio(0);
        __builtin_amdgcn_sched_barrier(0);
    }
#undef ASTAGE

    {
        float mfin = fmaxf(m_run, -8.0f);
        float aa   = __expf(m_run - mfin);
        float e8   = __expf(-8.0f - mfin);
        float nrem = (float)(S_ - ktend * 64);
        float lfin = l_run * aa + nrem * e8;
        float inv  = 1.0f / lfin;
#pragma unroll
        for (int r = 0; r < 16; ++r) {
            int dim0 = (r & 3) + 8 * (r >> 2) + 4 * hh;
            oT0[r] = (oT0[r] * aa + e8 * svs[dim0])      * inv;
            oT1[r] = (oT1[r] * aa + e8 * svs[dim0 + 32]) * inv;
        }
    }

    __syncthreads();
    float* Ob = (float*)SBUF + w * 2176;   // 32 rows x 68 floats per wave
#pragma unroll
    for (int r = 0; r < 16; ++r) {
        int dim0 = (r & 3) + 8 * (r >> 2) + 4 * hh;
        Ob[l31 * 68 + dim0]      = oT0[r];
        Ob[l31 * 68 + dim0 + 32] = oT1[r];
    }
    {
        const int qq = lane >> 1;
        const int ch = (lane & 1) * 32;
        const float* src = Ob + qq * 68 + ch;
        const int b  = bh >> 4;
        const int h  = bh & 15;
        float* dst = out + ((size_t)b * S_ + (q0 + w * 32 + qq)) * D_ + h * 64 + ch;
#pragma unroll
        for (int c = 0; c < 32; c += 4)
            *(float4*)(dst + c) = *(const float4*)(src + c);
    }
#undef KhiS
#undef KloS
#undef VtS
}

// ---------------------------------------------------------------------------
extern "C" void kernel_launch(void* const* d_in, const int* in_sizes, int n_in,
                              void* d_out, int out_size, void* d_ws, size_t ws_size,
                              hipStream_t stream) {
    const float* q  = (const float*)d_in[0];
    const float* k  = (const float*)d_in[1];
    const float* v  = (const float*)d_in[2];
    const float* wq = (const float*)d_in[4];
    const float* wk = (const float*)d_in[5];
    const float* wv = (const float*)d_in[6];
    float* out = (float*)d_out;

    char* ws = (char*)d_ws;
    // ws layout: x hi/lo [z]: z*16MB (+8MB for lo); wT hi/lo [z]: 48MB + z*4MB
    const short* XH[3] = {(short*)ws, (short*)(ws + 16777216), (short*)(ws + 33554432)};
    const short* XL[3] = {XH[0] + 4194304, XH[1] + 4194304, XH[2] + 4194304};
    const short* WH[3] = {(short*)(ws + 50331648), (short*)(ws + 54525952), (short*)(ws + 58720256)};
    const short* WL[3] = {WH[0] + 1048576, WH[1] + 1048576, WH[2] + 1048576};

    // Q/K/V projection outputs: workspace if it's big enough (keeps the
    // harness's input buffers clean); tightly packed at 60MB..100MB.
    short *Qhi, *Qlo, *Khi, *Klo, *Vt;
    if (ws_size >= (size_t)104857600) {            // 100 MB
        Qhi = (short*)(ws + 62914560);
        Qlo = (short*)(ws + 71303168);
        Khi = (short*)(ws + 79691776);
        Klo = (short*)(ws + 88080384);
        Vt  = (short*)(ws + 96468992);
    } else {
        Qhi = (short*)d_in[0]; Qlo = Qhi + 4194304;
        Khi = (short*)d_in[1]; Klo = Khi + 4194304;
        Vt  = (short*)d_in[2];
    }

    conv_all<<<dim3(13056), 256, 0, stream>>>(q, k, v, wq, wk, wv, ws);

    proj_mfma<<<dim3(8, 32, 3), 256, 0, stream>>>(
        XH[0], XL[0], XH[1], XL[1], XH[2], XL[2],
        WH[0], WL[0], WH[1], WL[1], WH[2], WL[2],
        Qhi, Qlo, Khi, Klo, Vt);

    attn_mfma<<<dim3(32, 16), 256, 0, stream>>>(Qhi, Qlo, Khi, Klo, Vt, out);
}

// Round 8
// 267.257 us; speedup vs baseline: 1.0313x; 1.0313x over previous
//
#include <hip/hip_runtime.h>
#include <hip/hip_bf16.h>

#define B_  2
#define S_  2048
#define D_  1024
#define H_  16
#define DH_ 64

typedef __attribute__((ext_vector_type(8)))  short  short8;
typedef __attribute__((ext_vector_type(4)))  short  short4b;
typedef __attribute__((ext_vector_type(16))) float  f32x16;

#define MFMA32(A,B,C) __builtin_amdgcn_mfma_f32_32x32x16_bf16(A,B,C,0,0,0)

static __device__ __forceinline__ short bf16b(float x) {
    __hip_bfloat16 h = __float2bfloat16(x);
    return *(short*)&h;
}
static __device__ __forceinline__ float bf16tof(short s) {
    union { unsigned u; float f; } cv;
    cv.u = ((unsigned)(unsigned short)s) << 16;
    return cv.f;
}
static __device__ __forceinline__ void gl2lds(const short* g, short* l) {
    __builtin_amdgcn_global_load_lds(
        (const __attribute__((address_space(1))) unsigned int*)g,
        (__attribute__((address_space(3))) unsigned int*)l, 16, 0, 0);
}
static __device__ __forceinline__ unsigned cvtpk(float a, float b) {
    unsigned r;
    asm("v_cvt_pk_bf16_f32 %0, %1, %2" : "=v"(r) : "v"(a), "v"(b));
    return r;   // low16 = bf16(a), high16 = bf16(b)
}
static __device__ __forceinline__ void pl32swap(unsigned &a, unsigned &b) {
    // a[32:63] <-> b[0:31]
    asm volatile("v_permlane32_swap_b32 %0, %1" : "+v"(a), "+v"(b));
}

// ---------------------------------------------------------------------------
// Merged conversion kernel.
//  bid < 12288 : x [4096x1024] fp32 -> hi/lo bf16 (3 z-slices of 4096 blocks)
//  bid >= 12288: w [k][n] fp32 -> wT hi/lo bf16 [n][k] (LDS-transposed tiles)
// ---------------------------------------------------------------------------
__global__ __launch_bounds__(256)
void conv_all(const float* __restrict__ q, const float* __restrict__ k,
              const float* __restrict__ v,
              const float* __restrict__ wq, const float* __restrict__ wk,
              const float* __restrict__ wv, char* __restrict__ ws) {
    __shared__ short HiT[64][80];
    __shared__ short LoT[64][80];
    const int bid = blockIdx.x;
    const int t   = threadIdx.x;
    if (bid < 12288) {
        const int z   = bid >> 12;           // 4096 blocks per z
        const int xb  = bid & 4095;
        const float* src = z == 0 ? q : z == 1 ? k : v;
        short* hi = (short*)(ws + (size_t)z * 16777216);
        short* lo = hi + 4194304;
        const int i = (xb * 256 + t) * 4;
        float4 xv = *(const float4*)&src[i];
        const float* xf = (const float*)&xv;
        short4b h4, l4;
#pragma unroll
        for (int e = 0; e < 4; ++e) {
            short hb = bf16b(xf[e]);
            h4[e] = hb;
            l4[e] = bf16b(xf[e] - bf16tof(hb));
        }
        *(short4b*)&hi[i] = h4;
        *(short4b*)&lo[i] = l4;
        return;
    }
    const int wid = bid - 12288;             // 768 blocks: 3 z x 256
    const int z   = wid >> 8;
    const int rem = wid & 255;
    const int k0  = (rem & 15) << 6, n0 = (rem >> 4) << 6;
    const float* w = z == 0 ? wq : z == 1 ? wk : wv;
    short* oh = (short*)(ws + 50331648 + (size_t)z * 4194304);  // 48MB + z*4MB
    short* ol = oh + 1048576;

    const int kr = t >> 2, c4 = (t & 3) * 16;
    const float* srow = w + (size_t)(k0 + kr) * 1024 + n0 + c4;
#pragma unroll
    for (int u = 0; u < 16; u += 4) {
        float4 f = *(const float4*)&srow[u];
        const float* ff = (const float*)&f;
#pragma unroll
        for (int e = 0; e < 4; ++e) {
            int nl = c4 + u + e;
            short hb = bf16b(ff[e]);
            HiT[nl][kr] = hb;
            LoT[nl][kr] = bf16b(ff[e] - bf16tof(hb));
        }
    }
    __syncthreads();
    const int nl = t >> 2, kc = (t & 3) * 16;
    size_t off = (size_t)(n0 + nl) * 1024 + k0 + kc;
    *(short8*)&oh[off]     = *(const short8*)&HiT[nl][kc];
    *(short8*)&oh[off + 8] = *(const short8*)&HiT[nl][kc + 8];
    *(short8*)&ol[off]     = *(const short8*)&LoT[nl][kc];
    *(short8*)&ol[off + 8] = *(const short8*)&LoT[nl][kc + 8];
}

// ---------------------------------------------------------------------------
// MFMA hi/lo projection GEMM — round 8: m201-style 4-phase schedule.
// Tile 256x256, BK=32, 8 waves (2M x 4N, wave tile 128x64). LDS 128 KB =
// 2 tile-buffers x 2 k-halves x {Ah|Al|Bh|Bl} (each 256x16 shorts, 8 KB).
// Per K-tile: 4 phases (kh, rm-pair): {ds_read frags; 2 gl2lds of next tile;
// s_barrier; lgkmcnt(0); 12 MFMA; s_barrier}. vmcnt(4) at end of P1/P3 —
// never 0 in steady state (the k-half granularity gives pipeline depth with
// only 2 tile buffers). Source-side swizzle p^((row>>2)&1) on 32B rows ->
// uniform 8-deep bank spread (b128 floor). Per-acc MFMA order identical to
// round 6 -> bit-identical output. z==0 output pre-scaled by 0.125.
// ---------------------------------------------------------------------------
#define QAH_ 0
#define QAL_ 4096
#define QBH_ 8192
#define QBL_ 12288

__global__ __launch_bounds__(512, 2)
void proj_mfma(const short* __restrict__ xh0, const short* __restrict__ xl0,
               const short* __restrict__ xh1, const short* __restrict__ xl1,
               const short* __restrict__ xh2, const short* __restrict__ xl2,
               const short* __restrict__ wh0, const short* __restrict__ wl0,
               const short* __restrict__ wh1, const short* __restrict__ wl1,
               const short* __restrict__ wh2, const short* __restrict__ wl2,
               short* __restrict__ qh, short* __restrict__ ql,
               short* __restrict__ kh, short* __restrict__ kl,
               short* __restrict__ vt) {
    __shared__ __align__(16) short lds[65536];   // 128 KB
    const int z  = blockIdx.z;
    const int m0 = blockIdx.y * 256;
    const int n0 = blockIdx.x * 256;
    const int t = threadIdx.x, lane = t & 63, w = t >> 6;
    const int l31 = lane & 31, hh = lane >> 5;
    const int wr = w >> 2, wc = w & 3;           // wave tile: rows wr*128, cols wc*64

    const short* xh = z == 0 ? xh0 : z == 1 ? xh1 : xh2;
    const short* xl = z == 0 ? xl0 : z == 1 ? xl1 : xl2;
    const short* wh = z == 0 ? wh0 : z == 1 ? wh1 : wh2;
    const short* wl = z == 0 ? wl0 : z == 1 ? wl1 : wl2;

    // ---- staging descriptors: per k-half, 4 gl2lds/thread (Ah,Al,Bh,Bl) ----
    const int c    = (w << 6) | lane;            // 0..511
    const int rowS = c >> 1, pq = c & 1;
    const int pqs8 = (pq ^ ((rowS >> 2) & 1)) * 8;   // swizzled source chunk
    const short* gAh = xh + (size_t)(m0 + rowS) * 1024 + pqs8;
    const short* gAl = xl + (size_t)(m0 + rowS) * 1024 + pqs8;
    const short* gBh = wh + (size_t)(n0 + rowS) * 1024 + pqs8;
    const short* gBl = wl + (size_t)(n0 + rowS) * 1024 + pqs8;
    const int wS = w << 9;                       // wave-uniform lds offset

    // ---- read addressing (within a k-half quarter: row*16 + (hh^sw)*8) ----
    const int co = ((hh ^ ((l31 >> 2) & 1)) << 3);
    int rA[4], rB[2];
#pragma unroll
    for (int p = 0; p < 4; ++p) rA[p] = (wr * 128 + p * 32 + l31) * 16 + co;
#pragma unroll
    for (int n = 0; n < 2; ++n) rB[n] = (wc * 64 + n * 32 + l31) * 16 + co;

    f32x16 acc[4][2] = {};

    // ---- prologue: stage tile 0 (k0 then k1), publish k0 ----
    gl2lds(gAh,      &lds[QAH_ + wS]);
    gl2lds(gBh,      &lds[QBH_ + wS]);
    gl2lds(gAl,      &lds[QAL_ + wS]);
    gl2lds(gBl,      &lds[QBL_ + wS]);
    gl2lds(gAh + 16, &lds[16384 + QAH_ + wS]);
    gl2lds(gBh + 16, &lds[16384 + QBH_ + wS]);
    gl2lds(gAl + 16, &lds[16384 + QAL_ + wS]);
    gl2lds(gBl + 16, &lds[16384 + QBL_ + wS]);
    asm volatile("s_waitcnt vmcnt(4)" ::: "memory");
    __builtin_amdgcn_s_barrier();

#define PHASE_MFMA(PA, PB)                                                    \
    acc[PA][0] = MFMA32(ah0, bh0k, acc[PA][0]);                               \
    acc[PA][1] = MFMA32(ah0, bh1k, acc[PA][1]);                               \
    acc[PB][0] = MFMA32(ah1, bh0k, acc[PB][0]);                               \
    acc[PB][1] = MFMA32(ah1, bh1k, acc[PB][1]);                               \
    acc[PA][0] = MFMA32(ah0, bl0k, acc[PA][0]);                               \
    acc[PA][1] = MFMA32(ah0, bl1k, acc[PA][1]);                               \
    acc[PB][0] = MFMA32(ah1, bl0k, acc[PB][0]);                               \
    acc[PB][1] = MFMA32(ah1, bl1k, acc[PB][1]);                               \
    acc[PA][0] = MFMA32(al0, bh0k, acc[PA][0]);                               \
    acc[PA][1] = MFMA32(al0, bh1k, acc[PA][1]);                               \
    acc[PB][0] = MFMA32(al1, bh0k, acc[PB][0]);                               \
    acc[PB][1] = MFMA32(al1, bh1k, acc[PB][1]);

    for (int kt = 0; kt < 32; ++kt) {
        const int tb = (kt & 1) << 15;           // current tile buffer
        const int nb = 32768 - tb;               // next tile buffer
        const int nk = (kt + 1) * 32;            // next tile global k (shorts)
        const bool st = (kt < 31);

        short8 bh0k, bh1k, bl0k, bl1k, ah0, ah1, al0, al1;

        // ===== P0: kh0, rm {0,1} =====
        __builtin_amdgcn_sched_barrier(0);
        bh0k = *(const short8*)&lds[tb + QBH_ + rB[0]];
        bh1k = *(const short8*)&lds[tb + QBH_ + rB[1]];
        bl0k = *(const short8*)&lds[tb + QBL_ + rB[0]];
        bl1k = *(const short8*)&lds[tb + QBL_ + rB[1]];
        ah0  = *(const short8*)&lds[tb + QAH_ + rA[0]];
        ah1  = *(const short8*)&lds[tb + QAH_ + rA[1]];
        al0  = *(const short8*)&lds[tb + QAL_ + rA[0]];
        al1  = *(const short8*)&lds[tb + QAL_ + rA[1]];
        if (st) { gl2lds(gAh + nk, &lds[nb + QAH_ + wS]);
                  gl2lds(gBh + nk, &lds[nb + QBH_ + wS]); }
        __builtin_amdgcn_s_barrier();
        asm volatile("s_waitcnt lgkmcnt(0)" ::: "memory");
        __builtin_amdgcn_sched_barrier(0);
        __builtin_amdgcn_s_setprio(1);
        PHASE_MFMA(0, 1)
        __builtin_amdgcn_s_setprio(0);
        __builtin_amdgcn_sched_barrier(0);
        __builtin_amdgcn_s_barrier();

        // ===== P1: kh0, rm {2,3} =====
        __builtin_amdgcn_sched_barrier(0);
        ah0 = *(const short8*)&lds[tb + QAH_ + rA[2]];
        ah1 = *(const short8*)&lds[tb + QAH_ + rA[3]];
        al0 = *(const short8*)&lds[tb + QAL_ + rA[2]];
        al1 = *(const short8*)&lds[tb + QAL_ + rA[3]];
        if (st) { gl2lds(gAl + nk, &lds[nb + QAL_ + wS]);
                  gl2lds(gBl + nk, &lds[nb + QBL_ + wS]);
                  asm volatile("s_waitcnt vmcnt(4)" ::: "memory");
        } else {  asm volatile("s_waitcnt vmcnt(0)" ::: "memory"); }
        __builtin_amdgcn_s_barrier();
        asm volatile("s_waitcnt lgkmcnt(0)" ::: "memory");
        __builtin_amdgcn_sched_barrier(0);
        __builtin_amdgcn_s_setprio(1);
        PHASE_MFMA(2, 3)
        __builtin_amdgcn_s_setprio(0);
        __builtin_amdgcn_sched_barrier(0);
        __builtin_amdgcn_s_barrier();

        // ===== P2: kh1, rm {0,1} =====
        __builtin_amdgcn_sched_barrier(0);
        bh0k = *(const short8*)&lds[tb + 16384 + QBH_ + rB[0]];
        bh1k = *(const short8*)&lds[tb + 16384 + QBH_ + rB[1]];
        bl0k = *(const short8*)&lds[tb + 16384 + QBL_ + rB[0]];
        bl1k = *(const short8*)&lds[tb + 16384 + QBL_ + rB[1]];
        ah0  = *(const short8*)&lds[tb + 16384 + QAH_ + rA[0]];
        ah1  = *(const short8*)&lds[tb + 16384 + QAH_ + rA[1]];
        al0  = *(const short8*)&lds[tb + 16384 + QAL_ + rA[0]];
        al1  = *(const short8*)&lds[tb + 16384 + QAL_ + rA[1]];
        if (st) { gl2lds(gAh + nk + 16, &lds[nb + 16384 + QAH_ + wS]);
                  gl2lds(gBh + nk + 16, &lds[nb + 16384 + QBH_ + wS]); }
        __builtin_amdgcn_s_barrier();
        asm volatile("s_waitcnt lgkmcnt(0)" ::: "memory");
        __builtin_amdgcn_sched_barrier(0);
        __builtin_amdgcn_s_setprio(1);
        PHASE_MFMA(0, 1)
        __builtin_amdgcn_s_setprio(0);
        __builtin_amdgcn_sched_barrier(0);
        __builtin_amdgcn_s_barrier();

        // ===== P3: kh1, rm {2,3} =====
        __builtin_amdgcn_sched_barrier(0);
        ah0 = *(const short8*)&lds[tb + 16384 + QAH_ + rA[2]];
        ah1 = *(const short8*)&lds[tb + 16384 + QAH_ + rA[3]];
        al0 = *(const short8*)&lds[tb + 16384 + QAL_ + rA[2]];
        al1 = *(const short8*)&lds[tb + 16384 + QAL_ + rA[3]];
        if (st) { gl2lds(gAl + nk + 16, &lds[nb + 16384 + QAL_ + wS]);
                  gl2lds(gBl + nk + 16, &lds[nb + 16384 + QBL_ + wS]);
                  asm volatile("s_waitcnt vmcnt(4)" ::: "memory"); }
        __builtin_amdgcn_s_barrier();
        asm volatile("s_waitcnt lgkmcnt(0)" ::: "memory");
        __builtin_amdgcn_sched_barrier(0);
        __builtin_amdgcn_s_setprio(1);
        PHASE_MFMA(2, 3)
        __builtin_amdgcn_s_setprio(0);
        __builtin_amdgcn_sched_barrier(0);
        __builtin_amdgcn_s_barrier();
    }
#undef PHASE_MFMA

    // ---- epilogue ----
    const int bb = m0 >> 11;
    const int sbase = (m0 & 2047) + wr * 128;
    if (z < 2) {
        short* oh = z == 0 ? qh : kh;
        short* ol = z == 0 ? ql : kl;
        const float qs = (z == 0) ? 0.125f : 1.0f;   // fold attn scale into Q
#pragma unroll
        for (int p = 0; p < 4; ++p)
#pragma unroll
        for (int nt = 0; nt < 2; ++nt) {
            int n_g = n0 + wc * 64 + nt * 32 + l31;
            int h = n_g >> 6, d = n_g & 63;
#pragma unroll
            for (int r = 0; r < 16; ++r) {
                int s = sbase + p * 32 + (r & 3) + 8 * (r >> 2) + 4 * hh;
                size_t off = (((size_t)(bb * 16 + h) * 2048 + s) << 6) + d;
                float a = acc[p][nt][r] * qs;
                short hb = bf16b(a);
                oh[off] = hb;
                ol[off] = bf16b(a - bf16tof(hb));
            }
        }
    } else {
#pragma unroll
        for (int p = 0; p < 4; ++p)
#pragma unroll
        for (int nt = 0; nt < 2; ++nt) {
            int n_g = n0 + wc * 64 + nt * 32 + l31;
            int h = n_g >> 6, d = n_g & 63;
            size_t vbase = ((size_t)(bb * 16 + h) * 64 + d) * 2048;
#pragma unroll
            for (int r2 = 0; r2 < 4; ++r2) {
                int s0 = sbase + p * 32 + 8 * r2 + 4 * hh;
                short4b pk;
#pragma unroll
                for (int a2 = 0; a2 < 4; ++a2)
                    pk[a2] = bf16b(acc[p][nt][r2 * 4 + a2]);
                *(short4b*)&vt[vbase + s0] = pk;
            }
        }
    }
}

// ---------------------------------------------------------------------------
// MFMA flash attention (unchanged from round 6).
// ---------------------------------------------------------------------------
__global__ __launch_bounds__(256, 2)
void attn_mfma(const short* __restrict__ Qhi, const short* __restrict__ Qlo,
               const short* __restrict__ Khi, const short* __restrict__ Klo,
               const short* __restrict__ Vt,  float* __restrict__ out) {
    __shared__ __align__(16) short SBUF[24576];   // 48KB: Khi|Klo|Vt (dbuf each)
    __shared__ float svp[4][64];
    __shared__ float svs[64];
#define KhiS (SBUF)
#define KloS (SBUF + 8192)
#define VtS  (SBUF + 16384)

    const int t     = threadIdx.x;
    const int lane  = t & 63;
    const int w     = t >> 6;
    const int l31   = lane & 31;
    const int hh    = lane >> 5;
    const int bh    = blockIdx.x;
    const int yy    = blockIdx.y;
    const int qt    = (yy < 8) ? yy : 23 - yy;
    const int q0    = qt * 128;
    const int myq   = q0 + w * 32 + l31;
    const int myq_min = q0 + w * 32;
    const int ktend = 2 * qt + 2;

    const size_t basebh = (size_t)bh * S_ * DH_;

    // ---- in-block V suffix sum over the all-masked tail ----
    {
        const int s_begin = ktend * 64;
        float part = 0.f;
        const short* vrow = Vt + basebh + (size_t)lane * S_;
        for (int s = s_begin + w * 8; s < S_; s += 32) {
            short8 vv = *(const short8*)&vrow[s];
#pragma unroll
            for (int e = 0; e < 8; ++e) part += bf16tof(vv[e]);
        }
        svp[w][lane] = part;
    }
    __syncthreads();
    if (t < 64)
        svs[t] = svp[0][t] + svp[1][t] + svp[2][t] + svp[3][t];
    // (consumed only in the epilogue; the loop's per-tile barriers order it)

    short8 qh[4], ql[4];
    {
        const short* qr = Qhi + basebh + (size_t)myq * DH_;
        const short* lr = Qlo + basebh + (size_t)myq * DH_;
#pragma unroll
        for (int kf = 0; kf < 4; ++kf) {
            int dofs = kf * 16 + hh * 8;
            qh[kf] = *(const short8*)(qr + dofs);
            ql[kf] = *(const short8*)(lr + dofs);
        }
    }

    // staging descriptors: 512 16B-chunks per 64x64 tile, 2 per thread.
    // chunk i -> lds row r=i>>3, chunk c=i&7; content = global chunk c^(r&7).
    const int i1 = (w << 6) | lane;       // 0..255
    const int i2 = 256 + i1;              // 256..511
    const int r1 = i1 >> 3, c1 = (i1 & 7) ^ (r1 & 7);
    const int r2 = i2 >> 3, c2 = (i2 & 7) ^ (r2 & 7);
    const short* gKh1 = Khi + basebh + (size_t)r1 * 64 + c1 * 8;
    const short* gKh2 = Khi + basebh + (size_t)r2 * 64 + c2 * 8;
    const short* gKl1 = Klo + basebh + (size_t)r1 * 64 + c1 * 8;
    const short* gKl2 = Klo + basebh + (size_t)r2 * 64 + c2 * 8;
    const short* gV1  = Vt  + basebh + (size_t)r1 * S_ + c1 * 8;
    const short* gV2  = Vt  + basebh + (size_t)r2 * S_ + c2 * 8;
    const int wub = w << 9;               // wave-uniform lds base (shorts)

#define ASTAGE(KT, BUF) do {                                                  \
        const int ka_ = (KT) * 4096, va_ = (KT) * 64, bo_ = (BUF) * 4096;     \
        gl2lds(gKh1 + ka_, &KhiS[bo_ + wub]);                                 \
        gl2lds(gKh2 + ka_, &KhiS[bo_ + 2048 + wub]);                          \
        gl2lds(gKl1 + ka_, &KloS[bo_ + wub]);                                 \
        gl2lds(gKl2 + ka_, &KloS[bo_ + 2048 + wub]);                          \
        gl2lds(gV1  + va_, &VtS [bo_ + wub]);                                 \
        gl2lds(gV2  + va_, &VtS [bo_ + 2048 + wub]);                          \
    } while (0)

    float m_run = -INFINITY, l_run = 0.f;
    f32x16 oT0 = {}, oT1 = {};

    const int sw0 = l31 & 7;              // read-swizzle ((l31+32)&7 == l31&7)

    ASTAGE(0, 0);

    for (int kt = 0; kt < ktend; ++kt) {
        const int bo = (kt & 1) << 12;
        // own tile-kt loads (issued last iter / prologue) must be complete
        // before the barrier; barrier then publishes all waves' staging.
        asm volatile("s_waitcnt vmcnt(0)" ::: "memory");
        __builtin_amdgcn_s_barrier();
        __builtin_amdgcn_sched_barrier(0);   // no hoisting above the barrier
        if (kt + 1 < ktend)
            ASTAGE(kt + 1, (kt & 1) ^ 1);
        __builtin_amdgcn_sched_barrier(0);   // keep stage issue before compute

        f32x16 acc0 = {}, acc1 = {};
        __builtin_amdgcn_s_setprio(1);
#pragma unroll
        for (int kf = 0; kf < 4; ++kf) {
            const int cs = ((2 * kf + hh) ^ sw0) << 3;
            short8 k0h = *(const short8*)&KhiS[bo + l31 * 64 + cs];
            short8 k0l = *(const short8*)&KloS[bo + l31 * 64 + cs];
            short8 k1h = *(const short8*)&KhiS[bo + (l31 + 32) * 64 + cs];
            short8 k1l = *(const short8*)&KloS[bo + (l31 + 32) * 64 + cs];
            acc0 = MFMA32(k0h, qh[kf], acc0);
            acc0 = MFMA32(k0h, ql[kf], acc0);
            acc0 = MFMA32(k0l, qh[kf], acc0);
            acc1 = MFMA32(k1h, qh[kf], acc1);
            acc1 = MFMA32(k1h, ql[kf], acc1);
            acc1 = MFMA32(k1l, qh[kf], acc1);
        }
        __builtin_amdgcn_s_setprio(0);

        float vals[32];
        float tmax;
        if (kt * 64 + 63 <= myq_min) {
            // fully-unmasked tile (wave-uniform): vals = acc directly
            float t0 = -INFINITY, t1 = -INFINITY;
#pragma unroll
            for (int r = 0; r < 16; ++r) {
                vals[r]      = acc0[r];
                vals[16 + r] = acc1[r];
                t0 = fmaxf(t0, acc0[r]);
                t1 = fmaxf(t1, acc1[r]);
            }
            tmax = fmaxf(t0, t1);
        } else {
            tmax = -INFINITY;
#pragma unroll
            for (int r = 0; r < 16; ++r) {
                int key0 = kt * 64 + ((r & 3) + 8 * (r >> 2) + 4 * hh);
                float v0 = (key0 <= myq)      ? acc0[r] : -8.0f;
                float v1 = (key0 + 32 <= myq) ? acc1[r] : -8.0f;
                vals[r] = v0;
                vals[16 + r] = v1;
                tmax = fmaxf(tmax, fmaxf(v0, v1));
            }
        }
        tmax = fmaxf(tmax, __shfl_xor(tmax, 32, 64));
        // defer-max (T13): keep m_run when the whole wave's tile-max is
        // within +8 of it; P is then bounded by e^8 (bf16-safe).
        const bool defer = __all(tmax <= m_run + 8.0f);
        if (!defer) {
            float mnew  = fmaxf(m_run, tmax);
            float alpha = __expf(m_run - mnew);
            l_run *= alpha;
#pragma unroll
            for (int r = 0; r < 16; ++r) { oT0[r] *= alpha; oT1[r] *= alpha; }
            m_run = mnew;
        }
        // T12: exp + pack in-register; psum on unrounded values.
        float psum = 0.f;
        unsigned cw[16];
#pragma unroll
        for (int tt = 0; tt < 16; ++tt) {
            float p0 = __expf(vals[2 * tt]     - m_run);
            float p1 = __expf(vals[2 * tt + 1] - m_run);
            psum += p0 + p1;
            cw[tt] = cvtpk(p0, p1);
        }
        psum += __shfl_xor(psum, 32, 64);
        l_run += psum;

        __builtin_amdgcn_s_setprio(1);
#pragma unroll
        for (int kf = 0; kf < 4; ++kf) {
            unsigned w0 = cw[4 * kf],     w1 = cw[4 * kf + 1];
            unsigned w2 = cw[4 * kf + 2], w3 = cw[4 * kf + 3];
            pl32swap(w0, w2);   // w0 = pf word q0, w2 = word q2
            pl32swap(w1, w3);   // w1 = word q1,    w3 = word q3
            union { unsigned u[4]; short8 s8; } pu;
            pu.u[0] = w0; pu.u[1] = w1; pu.u[2] = w2; pu.u[3] = w3;
            const int cs = ((2 * kf + hh) ^ sw0) << 3;
            short8 v0 = *(const short8*)&VtS[bo + l31 * 64 + cs];
            short8 v1 = *(const short8*)&VtS[bo + (l31 + 32) * 64 + cs];
            oT0 = MFMA32(v0, pu.s8, oT0);
            oT1 = MFMA32(v1, pu.s8, oT1);
        }
        __builtin_amdgcn_s_setprio(0);
        __builtin_amdgcn_sched_barrier(0);
    }
#undef ASTAGE

    {
        float mfin = fmaxf(m_run, -8.0f);
        float aa   = __expf(m_run - mfin);
        float e8   = __expf(-8.0f - mfin);
        float nrem = (float)(S_ - ktend * 64);
        float lfin = l_run * aa + nrem * e8;
        float inv  = 1.0f / lfin;
#pragma unroll
        for (int r = 0; r < 16; ++r) {
            int dim0 = (r & 3) + 8 * (r >> 2) + 4 * hh;
            oT0[r] = (oT0[r] * aa + e8 * svs[dim0])      * inv;
            oT1[r] = (oT1[r] * aa + e8 * svs[dim0 + 32]) * inv;
        }
    }

    __syncthreads();
    float* Ob = (float*)SBUF + w * 2176;   // 32 rows x 68 floats per wave
#pragma unroll
    for (int r = 0; r < 16; ++r) {
        int dim0 = (r & 3) + 8 * (r >> 2) + 4 * hh;
        Ob[l31 * 68 + dim0]      = oT0[r];
        Ob[l31 * 68 + dim0 + 32] = oT1[r];
    }
    {
        const int qq = lane >> 1;
        const int ch = (lane & 1) * 32;
        const float* src = Ob + qq * 68 + ch;
        const int b  = bh >> 4;
        const int h  = bh & 15;
        float* dst = out + ((size_t)b * S_ + (q0 + w * 32 + qq)) * D_ + h * 64 + ch;
#pragma unroll
        for (int c = 0; c < 32; c += 4)
            *(float4*)(dst + c) = *(const float4*)(src + c);
    }
#undef KhiS
#undef KloS
#undef VtS
}

// ---------------------------------------------------------------------------
extern "C" void kernel_launch(void* const* d_in, const int* in_sizes, int n_in,
                              void* d_out, int out_size, void* d_ws, size_t ws_size,
                              hipStream_t stream) {
    const float* q  = (const float*)d_in[0];
    const float* k  = (const float*)d_in[1];
    const float* v  = (const float*)d_in[2];
    const float* wq = (const float*)d_in[4];
    const float* wk = (const float*)d_in[5];
    const float* wv = (const float*)d_in[6];
    float* out = (float*)d_out;

    char* ws = (char*)d_ws;
    // ws layout: x hi/lo [z]: z*16MB (+8MB for lo); wT hi/lo [z]: 48MB + z*4MB
    const short* XH[3] = {(short*)ws, (short*)(ws + 16777216), (short*)(ws + 33554432)};
    const short* XL[3] = {XH[0] + 4194304, XH[1] + 4194304, XH[2] + 4194304};
    const short* WH[3] = {(short*)(ws + 50331648), (short*)(ws + 54525952), (short*)(ws + 58720256)};
    const short* WL[3] = {WH[0] + 1048576, WH[1] + 1048576, WH[2] + 1048576};

    // Q/K/V projection outputs: workspace if it's big enough (keeps the
    // harness's input buffers clean); tightly packed at 60MB..100MB.
    short *Qhi, *Qlo, *Khi, *Klo, *Vt;
    if (ws_size >= (size_t)104857600) {            // 100 MB
        Qhi = (short*)(ws + 62914560);
        Qlo = (short*)(ws + 71303168);
        Khi = (short*)(ws + 79691776);
        Klo = (short*)(ws + 88080384);
        Vt  = (short*)(ws + 96468992);
    } else {
        Qhi = (short*)d_in[0]; Qlo = Qhi + 4194304;
        Khi = (short*)d_in[1]; Klo = Khi + 4194304;
        Vt  = (short*)d_in[2];
    }

    conv_all<<<dim3(13056), 256, 0, stream>>>(q, k, v, wq, wk, wv, ws);

    proj_mfma<<<dim3(4, 16, 3), 512, 0, stream>>>(
        XH[0], XL[0], XH[1], XL[1], XH[2], XL[2],
        WH[0], WL[0], WH[1], WL[1], WH[2], WL[2],
        Qhi, Qlo, Khi, Klo, Vt);

    attn_mfma<<<dim3(32, 16), 256, 0, stream>>>(Qhi, Qlo, Khi, Klo, Vt, out);
}

// Round 9
// 266.354 us; speedup vs baseline: 1.0348x; 1.0034x over previous
//
#include <hip/hip_runtime.h>
#include <hip/hip_bf16.h>

#define B_  2
#define S_  2048
#define D_  1024
#define H_  16
#define DH_ 64

typedef __attribute__((ext_vector_type(8)))  short  short8;
typedef __attribute__((ext_vector_type(4)))  short  short4b;
typedef __attribute__((ext_vector_type(16))) float  f32x16;

#define MFMA32(A,B,C) __builtin_amdgcn_mfma_f32_32x32x16_bf16(A,B,C,0,0,0)

static __device__ __forceinline__ short bf16b(float x) {
    __hip_bfloat16 h = __float2bfloat16(x);
    return *(short*)&h;
}
static __device__ __forceinline__ float bf16tof(short s) {
    union { unsigned u; float f; } cv;
    cv.u = ((unsigned)(unsigned short)s) << 16;
    return cv.f;
}
static __device__ __forceinline__ void gl2lds(const short* g, short* l) {
    __builtin_amdgcn_global_load_lds(
        (const __attribute__((address_space(1))) unsigned int*)g,
        (__attribute__((address_space(3))) unsigned int*)l, 16, 0, 0);
}
static __device__ __forceinline__ unsigned cvtpk(float a, float b) {
    unsigned r;
    asm("v_cvt_pk_bf16_f32 %0, %1, %2" : "=v"(r) : "v"(a), "v"(b));
    return r;   // low16 = bf16(a), high16 = bf16(b)
}
static __device__ __forceinline__ void pl32swap(unsigned &a, unsigned &b) {
    // a[32:63] <-> b[0:31]
    asm volatile("v_permlane32_swap_b32 %0, %1" : "+v"(a), "+v"(b));
}

// ---------------------------------------------------------------------------
// Merged conversion kernel.
//  bid < 12288 : x [4096x1024] fp32 -> hi/lo bf16 (3 z-slices of 4096 blocks)
//  bid >= 12288: w [k][n] fp32 -> wT hi/lo bf16 [n][k] (LDS-transposed tiles)
// ---------------------------------------------------------------------------
__global__ __launch_bounds__(256)
void conv_all(const float* __restrict__ q, const float* __restrict__ k,
              const float* __restrict__ v,
              const float* __restrict__ wq, const float* __restrict__ wk,
              const float* __restrict__ wv, char* __restrict__ ws) {
    __shared__ short HiT[64][80];
    __shared__ short LoT[64][80];
    const int bid = blockIdx.x;
    const int t   = threadIdx.x;
    if (bid < 12288) {
        const int z   = bid >> 12;           // 4096 blocks per z
        const int xb  = bid & 4095;
        const float* src = z == 0 ? q : z == 1 ? k : v;
        short* hi = (short*)(ws + (size_t)z * 16777216);
        short* lo = hi + 4194304;
        const int i = (xb * 256 + t) * 4;
        float4 xv = *(const float4*)&src[i];
        const float* xf = (const float*)&xv;
        short4b h4, l4;
#pragma unroll
        for (int e = 0; e < 4; ++e) {
            short hb = bf16b(xf[e]);
            h4[e] = hb;
            l4[e] = bf16b(xf[e] - bf16tof(hb));
        }
        *(short4b*)&hi[i] = h4;
        *(short4b*)&lo[i] = l4;
        return;
    }
    const int wid = bid - 12288;             // 768 blocks: 3 z x 256
    const int z   = wid >> 8;
    const int rem = wid & 255;
    const int k0  = (rem & 15) << 6, n0 = (rem >> 4) << 6;
    const float* w = z == 0 ? wq : z == 1 ? wk : wv;
    short* oh = (short*)(ws + 50331648 + (size_t)z * 4194304);  // 48MB + z*4MB
    short* ol = oh + 1048576;

    const int kr = t >> 2, c4 = (t & 3) * 16;
    const float* srow = w + (size_t)(k0 + kr) * 1024 + n0 + c4;
#pragma unroll
    for (int u = 0; u < 16; u += 4) {
        float4 f = *(const float4*)&srow[u];
        const float* ff = (const float*)&f;
#pragma unroll
        for (int e = 0; e < 4; ++e) {
            int nl = c4 + u + e;
            short hb = bf16b(ff[e]);
            HiT[nl][kr] = hb;
            LoT[nl][kr] = bf16b(ff[e] - bf16tof(hb));
        }
    }
    __syncthreads();
    const int nl = t >> 2, kc = (t & 3) * 16;
    size_t off = (size_t)(n0 + nl) * 1024 + k0 + kc;
    *(short8*)&oh[off]     = *(const short8*)&HiT[nl][kc];
    *(short8*)&oh[off + 8] = *(const short8*)&HiT[nl][kc + 8];
    *(short8*)&ol[off]     = *(const short8*)&LoT[nl][kc];
    *(short8*)&ol[off + 8] = *(const short8*)&LoT[nl][kc + 8];
}

// ---------------------------------------------------------------------------
// MFMA hi/lo projection GEMM — round 9: 256x256 4-phase schedule with the
// PROVEN LDS geometry. Per tile-buffer, each array {Ah|Al|Bh|Bl} is [256][32]
// shorts (64B rows) with chunk swizzle p ^ ((row&3)^((row>>2)&3)) applied on
// the GLOBAL source (measured 0 bank conflicts in rounds 0-7). 2 buffers =
// 128 KB. Phases (ks, row-pair): P0{8 rd, stage Ah}, P1{4 rd, stage Al},
// P2{8 rd, stage Bh+Bl}, P3{4 rd; vmcnt(0) after MFMA -> publish next tile}.
// Each phase: reads/stage -> barrier -> lgkm(0) -> setprio(1) -> 12 MFMA ->
// setprio(0) -> barrier. Per-acc MFMA order identical to rounds 6-8 ->
// bit-identical output (absmax must stay exactly 1.25). z==0 pre-scaled .125.
// ---------------------------------------------------------------------------
#define AH_ 0
#define AL_ 8192
#define BH_ 16384
#define BL_ 24576

__global__ __launch_bounds__(512, 2)
void proj_mfma(const short* __restrict__ xh0, const short* __restrict__ xl0,
               const short* __restrict__ xh1, const short* __restrict__ xl1,
               const short* __restrict__ xh2, const short* __restrict__ xl2,
               const short* __restrict__ wh0, const short* __restrict__ wl0,
               const short* __restrict__ wh1, const short* __restrict__ wl1,
               const short* __restrict__ wh2, const short* __restrict__ wl2,
               short* __restrict__ qh, short* __restrict__ ql,
               short* __restrict__ kh, short* __restrict__ kl,
               short* __restrict__ vt) {
    __shared__ __align__(16) short lds[65536];   // 128 KB: 2 x 4 x [256][32]
    const int z  = blockIdx.z;
    const int m0 = blockIdx.y * 256;
    const int n0 = blockIdx.x * 256;
    const int t = threadIdx.x, lane = t & 63, w = t >> 6;
    const int l31 = lane & 31, hh = lane >> 5;
    const int wr = w >> 2, wc = w & 3;           // wave tile 128x64

    const short* xh = z == 0 ? xh0 : z == 1 ? xh1 : xh2;
    const short* xl = z == 0 ? xl0 : z == 1 ? xl1 : xl2;
    const short* wh = z == 0 ? wh0 : z == 1 ? wh1 : wh2;
    const short* wl = z == 0 ? wl0 : z == 1 ? wl1 : wl2;

    // staging: arrays 0=Ah 1=Al 2=Bh 3=Bl, 1024 chunks each, 2 per thread
    const short* gs[8];
    short*       ld8[8];
#pragma unroll
    for (int j = 0; j < 8; ++j) {
        const int arr = j >> 1;
        const int cc  = t + ((j & 1) << 9);      // 0..1023
        const int row = cc >> 2, p = cc & 3;
        const int kc  = p ^ ((row & 3) ^ ((row >> 2) & 3));
        const short* base = arr == 0 ? xh : arr == 1 ? xl : arr == 2 ? wh : wl;
        const int r0g = (arr < 2) ? m0 : n0;
        gs[j]  = base + (size_t)(r0g + row) * 1024 + kc * 8;
        ld8[j] = &lds[arr * 8192 + ((j & 1) << 12) + (w << 9)];  // wave-uniform
    }

    // read addressing: row*32 + ((kc ^ swl) << 3), kc = (ks<<1)|hh
    const int swl = (l31 & 3) ^ ((l31 >> 2) & 3);
    const int co0 = (hh ^ swl) << 3;
    const int co1 = ((2 | hh) ^ swl) << 3;
    int rA[4], rB[2];
#pragma unroll
    for (int p = 0; p < 4; ++p) rA[p] = (wr * 128 + p * 32 + l31) * 32;
#pragma unroll
    for (int n = 0; n < 2; ++n) rB[n] = (wc * 64 + n * 32 + l31) * 32;

    f32x16 acc[4][2] = {};

    // prologue: tile 0 -> buffer 0, publish
#pragma unroll
    for (int j = 0; j < 8; ++j)
        gl2lds(gs[j], ld8[j]);
    asm volatile("s_waitcnt vmcnt(0)" ::: "memory");
    __builtin_amdgcn_s_barrier();

#define PHASE_MFMA(PA, PB)                                                    \
    acc[PA][0] = MFMA32(ah0, bh0k, acc[PA][0]);                               \
    acc[PA][1] = MFMA32(ah0, bh1k, acc[PA][1]);                               \
    acc[PB][0] = MFMA32(ah1, bh0k, acc[PB][0]);                               \
    acc[PB][1] = MFMA32(ah1, bh1k, acc[PB][1]);                               \
    acc[PA][0] = MFMA32(ah0, bl0k, acc[PA][0]);                               \
    acc[PA][1] = MFMA32(ah0, bl1k, acc[PA][1]);                               \
    acc[PB][0] = MFMA32(ah1, bl0k, acc[PB][0]);                               \
    acc[PB][1] = MFMA32(ah1, bl1k, acc[PB][1]);                               \
    acc[PA][0] = MFMA32(al0, bh0k, acc[PA][0]);                               \
    acc[PA][1] = MFMA32(al0, bh1k, acc[PA][1]);                               \
    acc[PB][0] = MFMA32(al1, bh0k, acc[PB][0]);                               \
    acc[PB][1] = MFMA32(al1, bh1k, acc[PB][1]);

    for (int kt = 0; kt < 32; ++kt) {
        const int tb = (kt & 1) << 15;           // current buffer (shorts)
        const int nbo = 32768 - tb;              // next buffer offset
        const int nk = (kt + 1) * 32;
        const bool st = (kt < 31);

        short8 bh0k, bh1k, bl0k, bl1k, ah0, ah1, al0, al1;

        // ===== P0: ks0, rows {0,1}; stage Ah(t+1) =====
        __builtin_amdgcn_sched_barrier(0);
        bh0k = *(const short8*)&lds[tb + BH_ + rB[0] + co0];
        bh1k = *(const short8*)&lds[tb + BH_ + rB[1] + co0];
        bl0k = *(const short8*)&lds[tb + BL_ + rB[0] + co0];
        bl1k = *(const short8*)&lds[tb + BL_ + rB[1] + co0];
        ah0  = *(const short8*)&lds[tb + AH_ + rA[0] + co0];
        ah1  = *(const short8*)&lds[tb + AH_ + rA[1] + co0];
        al0  = *(const short8*)&lds[tb + AL_ + rA[0] + co0];
        al1  = *(const short8*)&lds[tb + AL_ + rA[1] + co0];
        if (st) { gl2lds(gs[0] + nk, ld8[0] + nbo);
                  gl2lds(gs[1] + nk, ld8[1] + nbo); }
        __builtin_amdgcn_s_barrier();
        asm volatile("s_waitcnt lgkmcnt(0)" ::: "memory");
        __builtin_amdgcn_sched_barrier(0);
        __builtin_amdgcn_s_setprio(1);
        PHASE_MFMA(0, 1)
        __builtin_amdgcn_s_setprio(0);
        __builtin_amdgcn_sched_barrier(0);
        __builtin_amdgcn_s_barrier();

        // ===== P1: ks0, rows {2,3}; stage Al(t+1) =====
        __builtin_amdgcn_sched_barrier(0);
        ah0 = *(const short8*)&lds[tb + AH_ + rA[2] + co0];
        ah1 = *(const short8*)&lds[tb + AH_ + rA[3] + co0];
        al0 = *(const short8*)&lds[tb + AL_ + rA[2] + co0];
        al1 = *(const short8*)&lds[tb + AL_ + rA[3] + co0];
        if (st) { gl2lds(gs[2] + nk, ld8[2] + nbo);
                  gl2lds(gs[3] + nk, ld8[3] + nbo); }
        __builtin_amdgcn_s_barrier();
        asm volatile("s_waitcnt lgkmcnt(0)" ::: "memory");
        __builtin_amdgcn_sched_barrier(0);
        __builtin_amdgcn_s_setprio(1);
        PHASE_MFMA(2, 3)
        __builtin_amdgcn_s_setprio(0);
        __builtin_amdgcn_sched_barrier(0);
        __builtin_amdgcn_s_barrier();

        // ===== P2: ks1, rows {0,1}; stage Bh+Bl(t+1) =====
        __builtin_amdgcn_sched_barrier(0);
        bh0k = *(const short8*)&lds[tb + BH_ + rB[0] + co1];
        bh1k = *(const short8*)&lds[tb + BH_ + rB[1] + co1];
        bl0k = *(const short8*)&lds[tb + BL_ + rB[0] + co1];
        bl1k = *(const short8*)&lds[tb + BL_ + rB[1] + co1];
        ah0  = *(const short8*)&lds[tb + AH_ + rA[0] + co1];
        ah1  = *(const short8*)&lds[tb + AH_ + rA[1] + co1];
        al0  = *(const short8*)&lds[tb + AL_ + rA[0] + co1];
        al1  = *(const short8*)&lds[tb + AL_ + rA[1] + co1];
        if (st) { gl2lds(gs[4] + nk, ld8[4] + nbo);
                  gl2lds(gs[5] + nk, ld8[5] + nbo);
                  gl2lds(gs[6] + nk, ld8[6] + nbo);
                  gl2lds(gs[7] + nk, ld8[7] + nbo); }
        __builtin_amdgcn_s_barrier();
        asm volatile("s_waitcnt lgkmcnt(0)" ::: "memory");
        __builtin_amdgcn_sched_barrier(0);
        __builtin_amdgcn_s_setprio(1);
        PHASE_MFMA(0, 1)
        __builtin_amdgcn_s_setprio(0);
        __builtin_amdgcn_sched_barrier(0);
        __builtin_amdgcn_s_barrier();

        // ===== P3: ks1, rows {2,3}; publish next tile at end =====
        __builtin_amdgcn_sched_barrier(0);
        ah0 = *(const short8*)&lds[tb + AH_ + rA[2] + co1];
        ah1 = *(const short8*)&lds[tb + AH_ + rA[3] + co1];
        al0 = *(const short8*)&lds[tb + AL_ + rA[2] + co1];
        al1 = *(const short8*)&lds[tb + AL_ + rA[3] + co1];
        __builtin_amdgcn_s_barrier();
        asm volatile("s_waitcnt lgkmcnt(0)" ::: "memory");
        __builtin_amdgcn_sched_barrier(0);
        __builtin_amdgcn_s_setprio(1);
        PHASE_MFMA(2, 3)
        __builtin_amdgcn_s_setprio(0);
        __builtin_amdgcn_sched_barrier(0);
        // only next-tile's 8 loads are outstanding here (~3 phases of cover)
        asm volatile("s_waitcnt vmcnt(0)" ::: "memory");
        __builtin_amdgcn_s_barrier();
    }
#undef PHASE_MFMA

    // ---- epilogue ----
    const int bb = m0 >> 11;
    const int sbase = (m0 & 2047) + wr * 128;
    if (z < 2) {
        short* oh = z == 0 ? qh : kh;
        short* ol = z == 0 ? ql : kl;
        const float qs = (z == 0) ? 0.125f : 1.0f;   // fold attn scale into Q
#pragma unroll
        for (int p = 0; p < 4; ++p)
#pragma unroll
        for (int nt = 0; nt < 2; ++nt) {
            int n_g = n0 + wc * 64 + nt * 32 + l31;
            int h = n_g >> 6, d = n_g & 63;
#pragma unroll
            for (int r = 0; r < 16; ++r) {
                int s = sbase + p * 32 + (r & 3) + 8 * (r >> 2) + 4 * hh;
                size_t off = (((size_t)(bb * 16 + h) * 2048 + s) << 6) + d;
                float a = acc[p][nt][r] * qs;
                short hb = bf16b(a);
                oh[off] = hb;
                ol[off] = bf16b(a - bf16tof(hb));
            }
        }
    } else {
#pragma unroll
        for (int p = 0; p < 4; ++p)
#pragma unroll
        for (int nt = 0; nt < 2; ++nt) {
            int n_g = n0 + wc * 64 + nt * 32 + l31;
            int h = n_g >> 6, d = n_g & 63;
            size_t vbase = ((size_t)(bb * 16 + h) * 64 + d) * 2048;
#pragma unroll
            for (int r2 = 0; r2 < 4; ++r2) {
                int s0 = sbase + p * 32 + 8 * r2 + 4 * hh;
                short4b pk;
#pragma unroll
                for (int a2 = 0; a2 < 4; ++a2)
                    pk[a2] = bf16b(acc[p][nt][r2 * 4 + a2]);
                *(short4b*)&vt[vbase + s0] = pk;
            }
        }
    }
}

// ---------------------------------------------------------------------------
// MFMA flash attention (unchanged from round 6).
// ---------------------------------------------------------------------------
__global__ __launch_bounds__(256, 2)
void attn_mfma(const short* __restrict__ Qhi, const short* __restrict__ Qlo,
               const short* __restrict__ Khi, const short* __restrict__ Klo,
               const short* __restrict__ Vt,  float* __restrict__ out) {
    __shared__ __align__(16) short SBUF[24576];   // 48KB: Khi|Klo|Vt (dbuf each)
    __shared__ float svp[4][64];
    __shared__ float svs[64];
#define KhiS (SBUF)
#define KloS (SBUF + 8192)
#define VtS  (SBUF + 16384)

    const int t     = threadIdx.x;
    const int lane  = t & 63;
    const int w     = t >> 6;
    const int l31   = lane & 31;
    const int hh    = lane >> 5;
    const int bh    = blockIdx.x;
    const int yy    = blockIdx.y;
    const int qt    = (yy < 8) ? yy : 23 - yy;
    const int q0    = qt * 128;
    const int myq   = q0 + w * 32 + l31;
    const int myq_min = q0 + w * 32;
    const int ktend = 2 * qt + 2;

    const size_t basebh = (size_t)bh * S_ * DH_;

    // ---- in-block V suffix sum over the all-masked tail ----
    {
        const int s_begin = ktend * 64;
        float part = 0.f;
        const short* vrow = Vt + basebh + (size_t)lane * S_;
        for (int s = s_begin + w * 8; s < S_; s += 32) {
            short8 vv = *(const short8*)&vrow[s];
#pragma unroll
            for (int e = 0; e < 8; ++e) part += bf16tof(vv[e]);
        }
        svp[w][lane] = part;
    }
    __syncthreads();
    if (t < 64)
        svs[t] = svp[0][t] + svp[1][t] + svp[2][t] + svp[3][t];
    // (consumed only in the epilogue; the loop's per-tile barriers order it)

    short8 qh[4], ql[4];
    {
        const short* qr = Qhi + basebh + (size_t)myq * DH_;
        const short* lr = Qlo + basebh + (size_t)myq * DH_;
#pragma unroll
        for (int kf = 0; kf < 4; ++kf) {
            int dofs = kf * 16 + hh * 8;
            qh[kf] = *(const short8*)(qr + dofs);
            ql[kf] = *(const short8*)(lr + dofs);
        }
    }

    // staging descriptors: 512 16B-chunks per 64x64 tile, 2 per thread.
    // chunk i -> lds row r=i>>3, chunk c=i&7; content = global chunk c^(r&7).
    const int i1 = (w << 6) | lane;       // 0..255
    const int i2 = 256 + i1;              // 256..511
    const int r1 = i1 >> 3, c1 = (i1 & 7) ^ (r1 & 7);
    const int r2 = i2 >> 3, c2 = (i2 & 7) ^ (r2 & 7);
    const short* gKh1 = Khi + basebh + (size_t)r1 * 64 + c1 * 8;
    const short* gKh2 = Khi + basebh + (size_t)r2 * 64 + c2 * 8;
    const short* gKl1 = Klo + basebh + (size_t)r1 * 64 + c1 * 8;
    const short* gKl2 = Klo + basebh + (size_t)r2 * 64 + c2 * 8;
    const short* gV1  = Vt  + basebh + (size_t)r1 * S_ + c1 * 8;
    const short* gV2  = Vt  + basebh + (size_t)r2 * S_ + c2 * 8;
    const int wub = w << 9;               // wave-uniform lds base (shorts)

#define ASTAGE(KT, BUF) do {                                                  \
        const int ka_ = (KT) * 4096, va_ = (KT) * 64, bo_ = (BUF) * 4096;     \
        gl2lds(gKh1 + ka_, &KhiS[bo_ + wub]);                                 \
        gl2lds(gKh2 + ka_, &KhiS[bo_ + 2048 + wub]);                          \
        gl2lds(gKl1 + ka_, &KloS[bo_ + wub]);                                 \
        gl2lds(gKl2 + ka_, &KloS[bo_ + 2048 + wub]);                          \
        gl2lds(gV1  + va_, &VtS [bo_ + wub]);                                 \
        gl2lds(gV2  + va_, &VtS [bo_ + 2048 + wub]);                          \
    } while (0)

    float m_run = -INFINITY, l_run = 0.f;
    f32x16 oT0 = {}, oT1 = {};

    const int sw0 = l31 & 7;              // read-swizzle ((l31+32)&7 == l31&7)

    ASTAGE(0, 0);

    for (int kt = 0; kt < ktend; ++kt) {
        const int bo = (kt & 1) << 12;
        // own tile-kt loads (issued last iter / prologue) must be complete
        // before the barrier; barrier then publishes all waves' staging.
        asm volatile("s_waitcnt vmcnt(0)" ::: "memory");
        __builtin_amdgcn_s_barrier();
        __builtin_amdgcn_sched_barrier(0);   // no hoisting above the barrier
        if (kt + 1 < ktend)
            ASTAGE(kt + 1, (kt & 1) ^ 1);
        __builtin_amdgcn_sched_barrier(0);   // keep stage issue before compute

        f32x16 acc0 = {}, acc1 = {};
        __builtin_amdgcn_s_setprio(1);
#pragma unroll
        for (int kf = 0; kf < 4; ++kf) {
            const int cs = ((2 * kf + hh) ^ sw0) << 3;
            short8 k0h = *(const short8*)&KhiS[bo + l31 * 64 + cs];
            short8 k0l = *(const short8*)&KloS[bo + l31 * 64 + cs];
            short8 k1h = *(const short8*)&KhiS[bo + (l31 + 32) * 64 + cs];
            short8 k1l = *(const short8*)&KloS[bo + (l31 + 32) * 64 + cs];
            acc0 = MFMA32(k0h, qh[kf], acc0);
            acc0 = MFMA32(k0h, ql[kf], acc0);
            acc0 = MFMA32(k0l, qh[kf], acc0);
            acc1 = MFMA32(k1h, qh[kf], acc1);
            acc1 = MFMA32(k1h, ql[kf], acc1);
            acc1 = MFMA32(k1l, qh[kf], acc1);
        }
        __builtin_amdgcn_s_setprio(0);

        float vals[32];
        float tmax;
        if (kt * 64 + 63 <= myq_min) {
            // fully-unmasked tile (wave-uniform): vals = acc directly
            float t0 = -INFINITY, t1 = -INFINITY;
#pragma unroll
            for (int r = 0; r < 16; ++r) {
                vals[r]      = acc0[r];
                vals[16 + r] = acc1[r];
                t0 = fmaxf(t0, acc0[r]);
                t1 = fmaxf(t1, acc1[r]);
            }
            tmax = fmaxf(t0, t1);
        } else {
            tmax = -INFINITY;
#pragma unroll
            for (int r = 0; r < 16; ++r) {
                int key0 = kt * 64 + ((r & 3) + 8 * (r >> 2) + 4 * hh);
                float v0 = (key0 <= myq)      ? acc0[r] : -8.0f;
                float v1 = (key0 + 32 <= myq) ? acc1[r] : -8.0f;
                vals[r] = v0;
                vals[16 + r] = v1;
                tmax = fmaxf(tmax, fmaxf(v0, v1));
            }
        }
        tmax = fmaxf(tmax, __shfl_xor(tmax, 32, 64));
        // defer-max (T13): keep m_run when the whole wave's tile-max is
        // within +8 of it; P is then bounded by e^8 (bf16-safe).
        const bool defer = __all(tmax <= m_run + 8.0f);
        if (!defer) {
            float mnew  = fmaxf(m_run, tmax);
            float alpha = __expf(m_run - mnew);
            l_run *= alpha;
#pragma unroll
            for (int r = 0; r < 16; ++r) { oT0[r] *= alpha; oT1[r] *= alpha; }
            m_run = mnew;
        }
        // T12: exp + pack in-register; psum on unrounded values.
        float psum = 0.f;
        unsigned cw[16];
#pragma unroll
        for (int tt = 0; tt < 16; ++tt) {
            float p0 = __expf(vals[2 * tt]     - m_run);
            float p1 = __expf(vals[2 * tt + 1] - m_run);
            psum += p0 + p1;
            cw[tt] = cvtpk(p0, p1);
        }
        psum += __shfl_xor(psum, 32, 64);
        l_run += psum;

        __builtin_amdgcn_s_setprio(1);
#pragma unroll
        for (int kf = 0; kf < 4; ++kf) {
            unsigned w0 = cw[4 * kf],     w1 = cw[4 * kf + 1];
            unsigned w2 = cw[4 * kf + 2], w3 = cw[4 * kf + 3];
            pl32swap(w0, w2);   // w0 = pf word q0, w2 = word q2
            pl32swap(w1, w3);   // w1 = word q1,    w3 = word q3
            union { unsigned u[4]; short8 s8; } pu;
            pu.u[0] = w0; pu.u[1] = w1; pu.u[2] = w2; pu.u[3] = w3;
            const int cs = ((2 * kf + hh) ^ sw0) << 3;
            short8 v0 = *(const short8*)&VtS[bo + l31 * 64 + cs];
            short8 v1 = *(const short8*)&VtS[bo + (l31 + 32) * 64 + cs];
            oT0 = MFMA32(v0, pu.s8, oT0);
            oT1 = MFMA32(v1, pu.s8, oT1);
        }
        __builtin_amdgcn_s_setprio(0);
        __builtin_amdgcn_sched_barrier(0);
    }
#undef ASTAGE

    {
        float mfin = fmaxf(m_run, -8.0f);
        float aa   = __expf(m_run - mfin);
        float e8   = __expf(-8.0f - mfin);
        float nrem = (float)(S_ - ktend * 64);
        float lfin = l_run * aa + nrem * e8;
        float inv  = 1.0f / lfin;
#pragma unroll
        for (int r = 0; r < 16; ++r) {
            int dim0 = (r & 3) + 8 * (r >> 2) + 4 * hh;
            oT0[r] = (oT0[r] * aa + e8 * svs[dim0])      * inv;
            oT1[r] = (oT1[r] * aa + e8 * svs[dim0 + 32]) * inv;
        }
    }

    __syncthreads();
    float* Ob = (float*)SBUF + w * 2176;   // 32 rows x 68 floats per wave
#pragma unroll
    for (int r = 0; r < 16; ++r) {
        int dim0 = (r & 3) + 8 * (r >> 2) + 4 * hh;
        Ob[l31 * 68 + dim0]      = oT0[r];
        Ob[l31 * 68 + dim0 + 32] = oT1[r];
    }
    {
        const int qq = lane >> 1;
        const int ch = (lane & 1) * 32;
        const float* src = Ob + qq * 68 + ch;
        const int b  = bh >> 4;
        const int h  = bh & 15;
        float* dst = out + ((size_t)b * S_ + (q0 + w * 32 + qq)) * D_ + h * 64 + ch;
#pragma unroll
        for (int c = 0; c < 32; c += 4)
            *(float4*)(dst + c) = *(const float4*)(src + c);
    }
#undef KhiS
#undef KloS
#undef VtS
}

// ---------------------------------------------------------------------------
extern "C" void kernel_launch(void* const* d_in, const int* in_sizes, int n_in,
                              void* d_out, int out_size, void* d_ws, size_t ws_size,
                              hipStream_t stream) {
    const float* q  = (const float*)d_in[0];
    const float* k  = (const float*)d_in[1];
    const float* v  = (const float*)d_in[2];
    const float* wq = (const float*)d_in[4];
    const float* wk = (const float*)d_in[5];
    const float* wv = (const float*)d_in[6];
    float* out = (float*)d_out;

    char* ws = (char*)d_ws;
    // ws layout: x hi/lo [z]: z*16MB (+8MB for lo); wT hi/lo [z]: 48MB + z*4MB
    const short* XH[3] = {(short*)ws, (short*)(ws + 16777216), (short*)(ws + 33554432)};
    const short* XL[3] = {XH[0] + 4194304, XH[1] + 4194304, XH[2] + 4194304};
    const short* WH[3] = {(short*)(ws + 50331648), (short*)(ws + 54525952), (short*)(ws + 58720256)};
    const short* WL[3] = {WH[0] + 1048576, WH[1] + 1048576, WH[2] + 1048576};

    // Q/K/V projection outputs: workspace if it's big enough (keeps the
    // harness's input buffers clean); tightly packed at 60MB..100MB.
    short *Qhi, *Qlo, *Khi, *Klo, *Vt;
    if (ws_size >= (size_t)104857600) {            // 100 MB
        Qhi = (short*)(ws + 62914560);
        Qlo = (short*)(ws + 71303168);
        Khi = (short*)(ws + 79691776);
        Klo = (short*)(ws + 88080384);
        Vt  = (short*)(ws + 96468992);
    } else {
        Qhi = (short*)d_in[0]; Qlo = Qhi + 4194304;
        Khi = (short*)d_in[1]; Klo = Khi + 4194304;
        Vt  = (short*)d_in[2];
    }

    conv_all<<<dim3(13056), 256, 0, stream>>>(q, k, v, wq, wk, wv, ws);

    proj_mfma<<<dim3(4, 16, 3), 512, 0, stream>>>(
        XH[0], XL[0], XH[1], XL[1], XH[2], XL[2],
        WH[0], WL[0], WH[1], WL[1], WH[2], WL[2],
        Qhi, Qlo, Khi, Klo, Vt);

    attn_mfma<<<dim3(32, 16), 256, 0, stream>>>(Qhi, Qlo, Khi, Klo, Vt, out);
}